// Round 1
// baseline (209.963 us; speedup 1.0000x reference)
//
#include <hip/hip_runtime.h>

#define B_ 16
#define N_ 1024
#define C_ 768
#define E_ 8
#define H_ 192
#define K_ 2

typedef __bf16 bf16x8 __attribute__((ext_vector_type(8)));
typedef float  f32x4  __attribute__((ext_vector_type(4)));

// ---------------------------------------------------------------------------
// Kernel 1: prep. (a) pack fc1_w/fc2_w to bf16 in MFMA-B-fragment order:
//   pw1[e][kb=c/32][n=h][c%32], pw2[e][kb=h/32][n=c][h%32]
// (b) transpose gate_w to gwT[d][j][c] (f32); rows 0..7 = clean, 8..15 = noise.
// ---------------------------------------------------------------------------
__global__ __launch_bounds__(256) void prep_kernel(
    const float* __restrict__ w1, const float* __restrict__ w2,
    const float* __restrict__ gw,
    __bf16* __restrict__ pw1, __bf16* __restrict__ pw2,
    float* __restrict__ gwT) {
  int idx = blockIdx.x * 256 + threadIdx.x;            // float4 index
  const int nW4 = (E_ * H_ * C_) / 4;                  // 294912
  if (idx >= nW4) return;
  int flat = idx * 4;
  int e = flat / (H_ * C_);
  int r = flat - e * (H_ * C_);

  // w1: [e][h][c] -> pw1
  {
    float4 a = *(const float4*)(w1 + (size_t)flat);
    int n = r / C_;           // h
    int c = r - n * C_;       // c, %4==0
    size_t o = ((size_t)(e * 24 + (c >> 5)) * 192 + n) * 32 + (c & 31);
    pw1[o + 0] = (__bf16)a.x; pw1[o + 1] = (__bf16)a.y;
    pw1[o + 2] = (__bf16)a.z; pw1[o + 3] = (__bf16)a.w;
  }
  // w2: [e][c][h] -> pw2
  {
    float4 a = *(const float4*)(w2 + (size_t)flat);
    int n = r / H_;           // c index 0..767
    int h = r - n * H_;       // 0..191, %4==0
    size_t o = ((size_t)(e * 6 + (h >> 5)) * 768 + n) * 32 + (h & 31);
    pw2[o + 0] = (__bf16)a.x; pw2[o + 1] = (__bf16)a.y;
    pw2[o + 2] = (__bf16)a.z; pw2[o + 3] = (__bf16)a.w;
  }
  // gwT: [d][c][16] -> [d][j][c]
  if (idx < (4 * 16 * C_) / 4) {
    int f = idx * 4;
    int d = f / (16 * C_);
    int rr = f - d * (16 * C_);
    int j = rr / C_;
    int c = rr - j * C_;      // %4==0
    const float* src = gw + (size_t)d * C_ * 16 + j;
    float4 v;
    v.x = src[(size_t)(c + 0) * 16]; v.y = src[(size_t)(c + 1) * 16];
    v.z = src[(size_t)(c + 2) * 16]; v.w = src[(size_t)(c + 3) * 16];
    *(float4*)(gwT + (size_t)f) = v;
  }
}

// ---------------------------------------------------------------------------
// Kernel 2: gating (noise half only). Grid = B*64 blocks, 16 tokens, 256 thr.
// Clean logits are linear in n: handled via xsum[b][c]=sum_n x (atomicAdd
// partials here; dotted with gw_clean inside expert_kernel). Thread =
// (token t, j) with e=j&7, half=j>>3: each thread dots 384 elems of the
// NOISE row; halves per-token FLOPs + LDS traffic vs the 16-dot version.
// ---------------------------------------------------------------------------
__global__ __launch_bounds__(256, 3) void gate_kernel(
    const float* __restrict__ x, const int* __restrict__ task_ids,
    const float* __restrict__ eps, const float* __restrict__ gwT,
    float* __restrict__ sums, float* __restrict__ xsum) {
  const int b = blockIdx.x >> 6;
  const int token0 = (blockIdx.x & 63) * 16;
  const int tid = threadIdx.x;

  __shared__ __align__(16) float xt[16][772];   // pad 4: 2-way (free) on reads
  __shared__ float sc[16][16];
  __shared__ float red[16][8];

  // stage 16x768 f32, coalesced
  const float* xbase = x + ((size_t)b * N_ + token0) * C_;
  for (int it = 0; it < 12; ++it) {
    int chunk = it * 256 + tid;                 // 0..3071
    int row = chunk / 192;
    int col4 = chunk - row * 192;
    float4 v = *(const float4*)(xbase + (size_t)row * C_ + col4 * 4);
    *(float4*)&xt[row][col4 * 4] = v;
  }
  __syncthreads();

  const int t = tid & 15;
  const int j = tid >> 4;
  const int e = j & 7;          // expert
  const int half = j >> 3;      // C-half: whole wave shares one half ->
                                // xt reads stay 16-distinct-rows (2-way, free)
  const int task = task_ids[b];
  const float* wrow = gwT + ((size_t)task * 16 + 8 + e) * C_ + half * 384;
  const float* xrow = &xt[t][half * 384];
  float acc = 0.0f;
#pragma unroll 4
  for (int c = 0; c < 384; c += 4) {
    float4 xv = *(const float4*)(xrow + c);
    float4 wv = *(const float4*)(wrow + c);
    acc += xv.x * wv.x + xv.y * wv.y + xv.z * wv.z + xv.w * wv.w;
  }
  sc[t][j] = acc;

  // xsum partials: 3 cols/thread (stride-3 cols -> 2-way LDS, free)
#pragma unroll
  for (int cc = 0; cc < 3; ++cc) {
    int col = tid * 3 + cc;
    float s = 0.0f;
#pragma unroll
    for (int tt = 0; tt < 16; ++tt) s += xt[tt][col];
    atomicAdd(&xsum[(size_t)b * C_ + col], s);
  }
  __syncthreads();

  if (tid < 128) {
    int t2 = tid & 15, e2 = tid >> 4;
    float raw = sc[t2][e2] + sc[t2][e2 + 8];
    float sp = (raw > 20.0f) ? raw : log1pf(expf(raw));
    red[t2][e2] = eps[((size_t)b * N_ + token0 + t2) * E_ + e2] * (sp + 0.01f);
  }
  __syncthreads();
  if (tid < 8) {
    float s = 0.0f;
#pragma unroll
    for (int tt = 0; tt < 16; ++tt) s += red[tt][tid];
    atomicAdd(&sums[b * E_ + tid], s);
  }
}

// ---------------------------------------------------------------------------
// Kernel 3: fused top-2 + 2-expert adapter. Grid = 256 blocks x 512 thr
// (8 waves = 2 token-halves x 4 N-slices), 64 tokens/block:
//  - halves per-token weight re-fetch (604 -> 302 MB of L2 traffic)
//  - XCD-pinned mapping: bid%8 = XCD, 2 samples/XCD -> each XCD's expert
//    working set <= 2.36 MB, L2-resident (no L3 round trips)
//  - prefetch depth 2 (3-phase rotation) to cover ~200cy L2 latency
// MFMA 16x16x32 bf16; C/D: col=lane&15, row=(lane>>4)*4+reg.
// ---------------------------------------------------------------------------
#define SMEM_EXPERT (64 * 776 * 2 + 64 * 200 * 2 + 32)   // 124960 B

__global__ __launch_bounds__(512, 2) void expert_kernel(
    const float* __restrict__ x, const __bf16* __restrict__ pw1,
    const __bf16* __restrict__ pw2, const float* __restrict__ fc1_b,
    const float* __restrict__ fc2_b, const float* __restrict__ sums,
    const float* __restrict__ xsum, const float* __restrict__ gwT,
    const int* __restrict__ task_ids, float* __restrict__ out) {
  const int bid = blockIdx.x;
  const int sxc = bid >> 3;                    // 0..31 within an XCD
  const int b = (bid & 7) * 2 + (sxc >> 4);    // 2 consecutive samples / XCD
  const int token0 = (sxc & 15) * 64;
  const int tid = threadIdx.x;
  const int wave = tid >> 6;
  const int wm = wave >> 2;                    // token half (0/1)
  const int wn = wave & 3;                     // N slice (0..3)
  const int lane = tid & 63;
  const int ln = lane & 15;
  const int q8 = (lane >> 4) * 8;
  const int q4 = (lane >> 4) * 4;
  const int arow = wm * 32;

  extern __shared__ char smem[];
  __bf16 (*xs)[776] = reinterpret_cast<__bf16(*)[776]>(smem);          // 99328
  __bf16 (*hs)[200] = reinterpret_cast<__bf16(*)[200]>(smem + 99328);  // 25600
  float* sm_clean = reinterpret_cast<float*>(smem + 99328 + 25600);    // 32

  // stage x tile 64x768 f32->bf16 (coalesced, b128 LDS writes)
  const float* xbase = x + ((size_t)b * N_ + token0) * C_;
  for (int it = 0; it < 12; ++it) {
    int chunk = it * 512 + tid;                // 0..6143
    int row = chunk / 96;
    int col8 = chunk - row * 96;
    const float* p = xbase + (size_t)row * C_ + col8 * 8;
    float4 v0 = *(const float4*)p;
    float4 v1 = *(const float4*)(p + 4);
    bf16x8 tv;
    tv[0] = (__bf16)v0.x; tv[1] = (__bf16)v0.y; tv[2] = (__bf16)v0.z; tv[3] = (__bf16)v0.w;
    tv[4] = (__bf16)v1.x; tv[5] = (__bf16)v1.y; tv[6] = (__bf16)v1.z; tv[7] = (__bf16)v1.w;
    *(bf16x8*)&xs[row][col8 * 8] = tv;
  }

  // clean gate logits (folded out of the gate kernel): wave e reduces
  // xsum[b] . gwT[task][e]; overlaps with the staging loads above.
  {
    const int task = task_ids[b];
    const float* xsb = xsum + (size_t)b * C_;
    const float* gr = gwT + ((size_t)task * 16 + wave) * C_;
    float cl = 0.0f;
#pragma unroll
    for (int c0 = 0; c0 < C_ / 64; ++c0) {
      int c = c0 * 64 + lane;
      cl += xsb[c] * gr[c];
    }
#pragma unroll
    for (int off = 32; off; off >>= 1) cl += __shfl_down(cl, off);
    if (lane == 0) sm_clean[wave] = cl + sums[b * E_ + wave];
  }
  __syncthreads();

  // top-2 (tie rule matches lax.top_k: strict >, stable)
  int e_idx[2]; float gate_v[2];
  {
    float best = -INFINITY, best2 = -INFINITY;
    int i1 = 0, i2 = 0;
#pragma unroll
    for (int e = 0; e < E_; ++e) {
      float v = sm_clean[e];
      if (v > best) { best2 = best; i2 = i1; best = v; i1 = e; }
      else if (v > best2) { best2 = v; i2 = e; }
    }
    float d = best - best2;
    float st = d / (d + 1e-6f);
    float et = expf(st);
    e_idx[0] = i1; gate_v[0] = et / (et + 1.0f);
    e_idx[1] = i2; gate_v[1] = 1.0f / (et + 1.0f);
  }

  f32x4 c2[2][12] = {};   // persistent y accumulator (gate folded into h)

  for (int kx = 0; kx < 2; ++kx) {
    const int e = e_idx[kx];
    const float g = gate_v[kx];

    // ---- GEMM1: h = x @ W1^T. M=64 (wm half x 2 frags), N-slice 48 (wn),
    // K=768 (24 kb). Depth-2 prefetch, 3-phase rotation, fully unrolled.
    const __bf16* w1l = pw1 + (size_t)e * (24 * 192 * 32)
                            + (size_t)(wn * 48 + ln) * 32 + q8;
    bf16x8 bq[3][3], aq[3][2];
#pragma unroll
    for (int k0 = 0; k0 < 2; ++k0) {
      const __bf16* nx = w1l + (size_t)k0 * 6144;
#pragma unroll
      for (int jj = 0; jj < 3; ++jj) bq[k0][jj] = *(const bf16x8*)(nx + jj * 512);
      aq[k0][0] = *(const bf16x8*)&xs[arow + ln][k0 * 32 + q8];
      aq[k0][1] = *(const bf16x8*)&xs[arow + 16 + ln][k0 * 32 + q8];
    }
    f32x4 c1[2][3] = {};
#pragma unroll
    for (int kb = 0; kb < 24; ++kb) {
      const int p = kb % 3;
      if (kb < 22) {
        const int kn = kb + 2, pn = kn % 3;
        const __bf16* nx = w1l + (size_t)kn * 6144;
#pragma unroll
        for (int jj = 0; jj < 3; ++jj) bq[pn][jj] = *(const bf16x8*)(nx + jj * 512);
        aq[pn][0] = *(const bf16x8*)&xs[arow + ln][kn * 32 + q8];
        aq[pn][1] = *(const bf16x8*)&xs[arow + 16 + ln][kn * 32 + q8];
      }
#pragma unroll
      for (int jj = 0; jj < 3; ++jj) {
        c1[0][jj] = __builtin_amdgcn_mfma_f32_16x16x32_bf16(aq[p][0], bq[p][jj], c1[0][jj], 0, 0, 0);
        c1[1][jj] = __builtin_amdgcn_mfma_f32_16x16x32_bf16(aq[p][1], bq[p][jj], c1[1][jj], 0, 0, 0);
      }
    }
    // bias + exact gelu + gate scale -> hs (bf16)
#pragma unroll
    for (int jj = 0; jj < 3; ++jj) {
      int col = wn * 48 + jj * 16 + ln;
      float b1 = fc1_b[e * H_ + col];
#pragma unroll
      for (int m = 0; m < 2; ++m) {
#pragma unroll
        for (int r = 0; r < 4; ++r) {
          int row = arow + m * 16 + q4 + r;
          float v = c1[m][jj][r] + b1;
          float gl = 0.5f * v * (1.0f + erff(v * 0.70710678118f));
          hs[row][col] = (__bf16)(g * gl);
        }
      }
    }
    __syncthreads();

    // ---- GEMM2: y += h @ W2^T. M=64 (wm half), N-slice 192 (wn), K=192.
    // 12 steps (6 kb x 2 half-tiles); B depth-2 (3-phase), A ping-pong on kb.
    const __bf16* w2l = pw2 + (size_t)e * (6 * 768 * 32)
                            + (size_t)(wn * 192 + ln) * 32 + q8;
    bf16x8 bh[3][6], av[2][2];
#pragma unroll
    for (int s0 = 0; s0 < 2; ++s0) {
#pragma unroll
      for (int jj = 0; jj < 6; ++jj)
        bh[s0][jj] = *(const bf16x8*)(w2l + (s0 * 6 + jj) * 512);
    }
    av[0][0] = *(const bf16x8*)&hs[arow + ln][q8];
    av[0][1] = *(const bf16x8*)&hs[arow + 16 + ln][q8];
#pragma unroll
    for (int st = 0; st < 12; ++st) {
      const int kb = st >> 1;
      const int half = st & 1;
      const int p = st % 3;
      if (st < 10) {
        const int s2 = st + 2;
        const int kb2 = s2 >> 1, half2 = s2 & 1, p2 = s2 % 3;
        const __bf16* src = w2l + (size_t)kb2 * 24576;
#pragma unroll
        for (int jj = 0; jj < 6; ++jj)
          bh[p2][jj] = *(const bf16x8*)(src + (half2 * 6 + jj) * 512);
        if (half2 == 0) {   // new kb 2 steps ahead: load its A frags
          av[kb2 & 1][0] = *(const bf16x8*)&hs[arow + ln][kb2 * 32 + q8];
          av[kb2 & 1][1] = *(const bf16x8*)&hs[arow + 16 + ln][kb2 * 32 + q8];
        }
      }
#pragma unroll
      for (int jj = 0; jj < 6; ++jj) {
        const int cj = half * 6 + jj;
        c2[0][cj] = __builtin_amdgcn_mfma_f32_16x16x32_bf16(av[kb & 1][0], bh[p][jj], c2[0][cj], 0, 0, 0);
        c2[1][cj] = __builtin_amdgcn_mfma_f32_16x16x32_bf16(av[kb & 1][1], bh[p][jj], c2[1][cj], 0, 0, 0);
      }
    }
    __syncthreads();   // protect hs before next expert overwrites
  }

  // epilogue: out = x + y (+ gate-weighted fc2_b)
  const float* xr = x + ((size_t)b * N_ + token0) * C_;
  float* outr = out + ((size_t)b * N_ + token0) * C_;
#pragma unroll
  for (int jj = 0; jj < 12; ++jj) {
    int col = wn * 192 + jj * 16 + ln;
    float b2t = gate_v[0] * fc2_b[e_idx[0] * C_ + col] +
                gate_v[1] * fc2_b[e_idx[1] * C_ + col];
#pragma unroll
    for (int m = 0; m < 2; ++m) {
#pragma unroll
      for (int r = 0; r < 4; ++r) {
        int row = arow + m * 16 + q4 + r;
        size_t off = (size_t)row * C_ + col;
        outr[off] = xr[off] + c2[m][jj][r] + b2t;
      }
    }
  }
}

// ---------------------------------------------------------------------------
extern "C" void kernel_launch(void* const* d_in, const int* in_sizes, int n_in,
                              void* d_out, int out_size, void* d_ws, size_t ws_size,
                              hipStream_t stream) {
  const float* x      = (const float*)d_in[0];
  const int*   task   = (const int*)d_in[1];
  const float* eps    = (const float*)d_in[2];
  const float* gate_w = (const float*)d_in[3];
  const float* fc1_w  = (const float*)d_in[4];
  const float* fc1_b  = (const float*)d_in[5];
  const float* fc2_w  = (const float*)d_in[6];
  const float* fc2_b  = (const float*)d_in[7];
  float* out = (float*)d_out;

  // workspace: pw1 | pw2 | gwT | sums | xsum  (~4.97 MB)
  const size_t nW = (size_t)E_ * H_ * C_;              // 1179648
  __bf16* pw1 = (__bf16*)d_ws;
  __bf16* pw2 = pw1 + nW;
  float* gwT  = (float*)((char*)d_ws + 2 * nW * sizeof(__bf16));
  float* sums = gwT + 4 * 16 * C_;
  float* xsum = sums + B_ * E_;

  hipMemsetAsync(sums, 0, (B_ * E_ + B_ * C_) * sizeof(float), stream);
  prep_kernel<<<(nW / 4 + 255) / 256, 256, 0, stream>>>(fc1_w, fc2_w, gate_w,
                                                        pw1, pw2, gwT);
  gate_kernel<<<B_ * 64, 256, 0, stream>>>(x, task, eps, gwT, sums, xsum);

  hipFuncSetAttribute(reinterpret_cast<const void*>(expert_kernel),
                      hipFuncAttributeMaxDynamicSharedMemorySize, SMEM_EXPERT);
  expert_kernel<<<B_ * 16, 512, SMEM_EXPERT, stream>>>(
      x, pw1, pw2, fc1_b, fc2_b, sums, xsum, gwT, task, out);
}